// Round 1
// baseline (87.999 us; speedup 1.0000x reference)
//
#include <hip/hip_runtime.h>

// EncodingLayer: B=16, N=1024 (32x32), D=128, K=32
//   A = softmax_k( scale_k * ||x_n - c_k||^2 )
//   E[b,k,d] = sum_n A[b,n,k]*x[b,n,d] - (sum_n A[b,n,k]) * c[k,d]
//
// One fused kernel: 256 blocks = 16 batches x 16 splits of 64 pixels.
// Each block computes its partial E (with its partial a_sum*c already
// subtracted -- the correction distributes over splits) and atomicAdds
// into d_out, which is memset to 0 on the stream first.

constexpr int NPB = 64;   // pixels per block
constexpr int XS  = 132;  // padded LDS row stride (128 + 4) -> bank-conflict-free

__global__ __launch_bounds__(256)
void enc_kernel(const float* __restrict__ x, const float* __restrict__ cw,
                const float* __restrict__ scale, float* __restrict__ out)
{
    __shared__ float x_s[NPB * XS];   // 33.0 KB
    __shared__ float A_s[NPB * 32];   //  8.0 KB
    __shared__ float x2_s[NPB];
    __shared__ float asum_s[4 * 32];

    const int tid = threadIdx.x;
    const int b   = blockIdx.x >> 4;
    const int s   = blockIdx.x & 15;

    // ---- stage x chunk: 64 pixels x 128 floats, coalesced float4 ----
    const float4* xg4 = (const float4*)(x + (size_t)(b * 1024 + s * NPB) * 128);
#pragma unroll
    for (int i = 0; i < 8; ++i) {
        int f = tid + 256 * i;            // float4 index in chunk (2048 total)
        float4 v = xg4[f];
        *(float4*)&x_s[(f >> 5) * XS + (f & 31) * 4] = v;
    }

    // ---- codeword fragment in registers: lane(k,h) holds c[k][h*64 .. +63] ----
    const int lane = tid & 63;
    const int k    = lane & 31;
    const int h    = lane >> 5;
    const int w    = tid >> 6;

    float4 cf[16];
    const float4* cw4 = (const float4*)(cw + k * 128 + h * 64);
    float c2 = 0.f;
#pragma unroll
    for (int i = 0; i < 16; ++i) {
        float4 c = cw4[i];
        cf[i] = c;
        c2 += c.x * c.x + c.y * c.y + c.z * c.z + c.w * c.w;
    }
    c2 += __shfl_xor(c2, 32);   // combine halves -> full ||c_k||^2 in both halves
    const float sck = scale[k];

    __syncthreads();

    // ---- pre-phase: x2[n] = ||x_n||^2 (4 threads per pixel) ----
    {
        int p = tid >> 2, q = tid & 3;
        float ss = 0.f;
#pragma unroll
        for (int i = 0; i < 8; ++i) {
            float4 v = *(const float4*)&x_s[p * XS + q * 32 + 4 * i];
            ss += v.x * v.x + v.y * v.y + v.z * v.z + v.w * v.w;
        }
        ss += __shfl_xor(ss, 1);
        ss += __shfl_xor(ss, 2);
        if (q == 0) x2_s[p] = ss;
    }
    __syncthreads();

    // ---- phase 1: per-pixel softmax over K=32, one wave per 16 pixels ----
    float a_part = 0.f;
#pragma unroll 2
    for (int p = 0; p < 16; ++p) {
        const int n = (w << 4) + p;
        const float4* xr = (const float4*)&x_s[n * XS + h * 64];
        float xc = 0.f;
#pragma unroll
        for (int i = 0; i < 16; ++i) {
            float4 v = xr[i];   // broadcast read (2 distinct addrs per wave)
            xc += v.x * cf[i].x + v.y * cf[i].y + v.z * cf[i].z + v.w * cf[i].w;
        }
        xc += __shfl_xor(xc, 32);   // combine d-halves -> full dot(x_n, c_k)

        float sl = sck * (x2_s[n] - 2.f * xc + c2);
        // softmax over k: butterfly within each 32-lane half (masks <= 16)
        float m = sl;
#pragma unroll
        for (int msk = 16; msk >= 1; msk >>= 1) m = fmaxf(m, __shfl_xor(m, msk));
        float e = __expf(sl - m);
        float den = e;
#pragma unroll
        for (int msk = 16; msk >= 1; msk >>= 1) den += __shfl_xor(den, msk);
        float a = e / den;
        A_s[n * 32 + k] = a;        // both halves write identical value (benign)
        a_part += a;
    }
    if (h == 0) asum_s[w * 32 + k] = a_part;
    __syncthreads();

    // ---- phase 2: E_part[k][d] = sum_n A[n][k] * x[n][d], 4k x 4d per thread ----
    {
        const int kg = tid >> 5;    // 0..7  -> k quad
        const int dg = tid & 31;    // 0..31 -> d quad
        float acc[4][4];
#pragma unroll
        for (int i = 0; i < 4; ++i)
#pragma unroll
            for (int j = 0; j < 4; ++j) acc[i][j] = 0.f;

#pragma unroll 4
        for (int n = 0; n < NPB; ++n) {
            float4 a4 = *(const float4*)&A_s[n * 32 + kg * 4];  // broadcast
            float4 x4 = *(const float4*)&x_s[n * XS + dg * 4];  // conflict-free
            acc[0][0] += a4.x * x4.x; acc[0][1] += a4.x * x4.y;
            acc[0][2] += a4.x * x4.z; acc[0][3] += a4.x * x4.w;
            acc[1][0] += a4.y * x4.x; acc[1][1] += a4.y * x4.y;
            acc[1][2] += a4.y * x4.z; acc[1][3] += a4.y * x4.w;
            acc[2][0] += a4.z * x4.x; acc[2][1] += a4.z * x4.y;
            acc[2][2] += a4.z * x4.z; acc[2][3] += a4.z * x4.w;
            acc[3][0] += a4.w * x4.x; acc[3][1] += a4.w * x4.y;
            acc[3][2] += a4.w * x4.z; acc[3][3] += a4.w * x4.w;
        }

        // fold in this block's partial -a_sum * c, then accumulate to global
        float as[4];
#pragma unroll
        for (int i = 0; i < 4; ++i)
            as[i] = asum_s[kg * 4 + i] + asum_s[32 + kg * 4 + i] +
                    asum_s[64 + kg * 4 + i] + asum_s[96 + kg * 4 + i];

        float* ob = out + (size_t)b * 4096;
#pragma unroll
        for (int i = 0; i < 4; ++i) {
            const int kk = kg * 4 + i;
            float4 c4 = *(const float4*)&cw[kk * 128 + dg * 4];
            acc[i][0] -= as[i] * c4.x;
            acc[i][1] -= as[i] * c4.y;
            acc[i][2] -= as[i] * c4.z;
            acc[i][3] -= as[i] * c4.w;
            const int base = kk * 128 + dg * 4;
            atomicAdd(&ob[base + 0], acc[i][0]);
            atomicAdd(&ob[base + 1], acc[i][1]);
            atomicAdd(&ob[base + 2], acc[i][2]);
            atomicAdd(&ob[base + 3], acc[i][3]);
        }
    }
}

extern "C" void kernel_launch(void* const* d_in, const int* in_sizes, int n_in,
                              void* d_out, int out_size, void* d_ws, size_t ws_size,
                              hipStream_t stream)
{
    const float* x     = (const float*)d_in[0];  // [16,32,32,128]
    const float* cw    = (const float*)d_in[1];  // [32,128]
    const float* scale = (const float*)d_in[2];  // [32]
    float* out = (float*)d_out;                  // [16,32,128]

    hipMemsetAsync(out, 0, (size_t)out_size * sizeof(float), stream);
    enc_kernel<<<256, 256, 0, stream>>>(x, cw, scale, out);
}

// Round 2
// 78.465 us; speedup vs baseline: 1.1215x; 1.1215x over previous
//
#include <hip/hip_runtime.h>

// EncodingLayer: B=16, N=1024 (32x32), D=128, K=32
//   A = softmax_k( scale_k * ||x_n - c_k||^2 )
//   E[b,k,d] = sum_n A[b,n,k]*x[b,n,d] - (sum_n A[b,n,k]) * c[k,d]
//
// k1: 256 blocks = 16 batches x 16 splits of 64 pixels. Each block computes
//     its partial E (its partial a_sum*c already folded in -- the correction
//     distributes over splits) and stores it to d_ws[(b*16+s)*4096 .. +4096).
//     No atomics, no output memset.
// k2: 64 blocks x 256 threads sum the 16 slices per batch into d_out.
//     4 MB of ws traffic, mostly L2-resident.

constexpr int NPB = 64;   // pixels per block
constexpr int XS  = 132;  // padded LDS row stride (128 + 4) -> bank-conflict-free

__global__ __launch_bounds__(256)
void enc_partial(const float* __restrict__ x, const float* __restrict__ cw,
                 const float* __restrict__ scale, float* __restrict__ ws)
{
    __shared__ float x_s[NPB * XS];   // 33.0 KB
    __shared__ float A_s[NPB * 32];   //  8.0 KB
    __shared__ float x2_s[NPB];
    __shared__ float asum_s[4 * 32];

    const int tid = threadIdx.x;
    const int b   = blockIdx.x >> 4;
    const int s   = blockIdx.x & 15;

    // ---- stage x chunk: 64 pixels x 128 floats, coalesced float4 ----
    const float4* xg4 = (const float4*)(x + (size_t)(b * 1024 + s * NPB) * 128);
#pragma unroll
    for (int i = 0; i < 8; ++i) {
        int f = tid + 256 * i;            // float4 index in chunk (2048 total)
        float4 v = xg4[f];
        *(float4*)&x_s[(f >> 5) * XS + (f & 31) * 4] = v;
    }

    // ---- codeword fragment in registers: lane(k,h) holds c[k][h*64 .. +63] ----
    const int lane = tid & 63;
    const int k    = lane & 31;
    const int h    = lane >> 5;
    const int w    = tid >> 6;

    float4 cf[16];
    const float4* cw4 = (const float4*)(cw + k * 128 + h * 64);
    float c2 = 0.f;
#pragma unroll
    for (int i = 0; i < 16; ++i) {
        float4 c = cw4[i];
        cf[i] = c;
        c2 += c.x * c.x + c.y * c.y + c.z * c.z + c.w * c.w;
    }
    c2 += __shfl_xor(c2, 32);   // combine halves -> full ||c_k||^2 in both halves
    const float sck = scale[k];

    __syncthreads();

    // ---- pre-phase: x2[n] = ||x_n||^2 (4 threads per pixel) ----
    {
        int p = tid >> 2, q = tid & 3;
        float ss = 0.f;
#pragma unroll
        for (int i = 0; i < 8; ++i) {
            float4 v = *(const float4*)&x_s[p * XS + q * 32 + 4 * i];
            ss += v.x * v.x + v.y * v.y + v.z * v.z + v.w * v.w;
        }
        ss += __shfl_xor(ss, 1);
        ss += __shfl_xor(ss, 2);
        if (q == 0) x2_s[p] = ss;
    }
    __syncthreads();

    // ---- phase 1: per-pixel softmax over K=32, one wave per 16 pixels ----
    float a_part = 0.f;
#pragma unroll 2
    for (int p = 0; p < 16; ++p) {
        const int n = (w << 4) + p;
        const float4* xr = (const float4*)&x_s[n * XS + h * 64];
        float xc = 0.f;
#pragma unroll
        for (int i = 0; i < 16; ++i) {
            float4 v = xr[i];   // broadcast read (2 distinct addrs per wave)
            xc += v.x * cf[i].x + v.y * cf[i].y + v.z * cf[i].z + v.w * cf[i].w;
        }
        xc += __shfl_xor(xc, 32);   // combine d-halves -> full dot(x_n, c_k)

        float sl = sck * (x2_s[n] - 2.f * xc + c2);
        // softmax over k: butterfly within each 32-lane half (masks <= 16)
        float m = sl;
#pragma unroll
        for (int msk = 16; msk >= 1; msk >>= 1) m = fmaxf(m, __shfl_xor(m, msk));
        float e = __expf(sl - m);
        float den = e;
#pragma unroll
        for (int msk = 16; msk >= 1; msk >>= 1) den += __shfl_xor(den, msk);
        float a = e / den;
        A_s[n * 32 + k] = a;        // both halves write identical value (benign)
        a_part += a;
    }
    if (h == 0) asum_s[w * 32 + k] = a_part;
    __syncthreads();

    // ---- phase 2: E_part[k][d] = sum_n A[n][k] * x[n][d], 4k x 4d per thread ----
    {
        const int kg = tid >> 5;    // 0..7  -> k quad
        const int dg = tid & 31;    // 0..31 -> d quad
        float acc[4][4];
#pragma unroll
        for (int i = 0; i < 4; ++i)
#pragma unroll
            for (int j = 0; j < 4; ++j) acc[i][j] = 0.f;

#pragma unroll 8
        for (int n = 0; n < NPB; ++n) {
            float4 a4 = *(const float4*)&A_s[n * 32 + kg * 4];  // broadcast
            float4 x4 = *(const float4*)&x_s[n * XS + dg * 4];  // conflict-free
            acc[0][0] += a4.x * x4.x; acc[0][1] += a4.x * x4.y;
            acc[0][2] += a4.x * x4.z; acc[0][3] += a4.x * x4.w;
            acc[1][0] += a4.y * x4.x; acc[1][1] += a4.y * x4.y;
            acc[1][2] += a4.y * x4.z; acc[1][3] += a4.y * x4.w;
            acc[2][0] += a4.z * x4.x; acc[2][1] += a4.z * x4.y;
            acc[2][2] += a4.z * x4.z; acc[2][3] += a4.z * x4.w;
            acc[3][0] += a4.w * x4.x; acc[3][1] += a4.w * x4.y;
            acc[3][2] += a4.w * x4.z; acc[3][3] += a4.w * x4.w;
        }

        // fold in this block's partial -a_sum * c, store partial slice to ws
        float as[4];
#pragma unroll
        for (int i = 0; i < 4; ++i)
            as[i] = asum_s[kg * 4 + i] + asum_s[32 + kg * 4 + i] +
                    asum_s[64 + kg * 4 + i] + asum_s[96 + kg * 4 + i];

        float* wb = ws + (size_t)(b * 16 + s) * 4096;
#pragma unroll
        for (int i = 0; i < 4; ++i) {
            const int kk = kg * 4 + i;
            float4 c4 = *(const float4*)&cw[kk * 128 + dg * 4];
            float4 r;
            r.x = acc[i][0] - as[i] * c4.x;
            r.y = acc[i][1] - as[i] * c4.y;
            r.z = acc[i][2] - as[i] * c4.z;
            r.w = acc[i][3] - as[i] * c4.w;
            *(float4*)&wb[kk * 128 + dg * 4] = r;   // coalesced, no atomics
        }
    }
}

// Sum the 16 per-split slices per batch: out[b][j] = sum_s ws[(b*16+s)*4096 + j]
__global__ __launch_bounds__(256)
void enc_reduce(const float* __restrict__ ws, float* __restrict__ out)
{
    const int gid = blockIdx.x * 256 + threadIdx.x;   // 0..16383 float4-quads
    const int b   = gid >> 10;                        // 1024 quads per batch
    const int j4  = gid & 1023;
    const float4* base = (const float4*)ws + (size_t)b * 16384 + j4;
    float4 acc = {0.f, 0.f, 0.f, 0.f};
#pragma unroll
    for (int s = 0; s < 16; ++s) {
        float4 v = base[(size_t)s * 1024];            // coalesced within wave
        acc.x += v.x; acc.y += v.y; acc.z += v.z; acc.w += v.w;
    }
    ((float4*)out)[gid] = acc;
}

extern "C" void kernel_launch(void* const* d_in, const int* in_sizes, int n_in,
                              void* d_out, int out_size, void* d_ws, size_t ws_size,
                              hipStream_t stream)
{
    const float* x     = (const float*)d_in[0];  // [16,32,32,128]
    const float* cw    = (const float*)d_in[1];  // [32,128]
    const float* scale = (const float*)d_in[2];  // [32]
    float* out = (float*)d_out;                  // [16,32,128]
    float* ws  = (float*)d_ws;                   // uses 4 MB of workspace

    enc_partial<<<256, 256, 0, stream>>>(x, cw, scale, ws);
    enc_reduce<<<64, 256, 0, stream>>>(ws, out);
}

// Round 3
// 75.940 us; speedup vs baseline: 1.1588x; 1.0332x over previous
//
#include <hip/hip_runtime.h>

// EncodingLayer: B=16, N=1024 (32x32), D=128, K=32
//   A = softmax_k( scale_k * ||x_n - c_k||^2 )
//   E[b,k,d] = sum_n A[b,n,k]*x[b,n,d] - (sum_n A[b,n,k]) * c[k,d]
//
// k1: 512 blocks = 16 batches x 32 splits of 32 pixels (2 blocks/CU -> 2
//     waves/SIMD for latency overlap). Each block computes its partial E
//     (partial a_sum*c folded in) and stores to d_ws[(b*32+s)*4096 .. +4096).
// k2: 64 blocks x 256 threads sum the 32 slices per batch into d_out.
//
// Phase-1 dot products use 4 independent accumulators to cut the FMA
// dependency chain 4x (we are latency-bound at low occupancy).

constexpr int NPB = 32;   // pixels per block
constexpr int XS  = 132;  // padded LDS row stride (128 + 4) -> bank-conflict-free

__global__ __launch_bounds__(256)
void enc_partial(const float* __restrict__ x, const float* __restrict__ cw,
                 const float* __restrict__ scale, float* __restrict__ ws)
{
    __shared__ float x_s[NPB * XS];   // 16.5 KB
    __shared__ float A_s[NPB * 32];   //  4.0 KB
    __shared__ float x2_s[NPB];
    __shared__ float asum_s[4 * 32];

    const int tid = threadIdx.x;
    const int b   = blockIdx.x >> 5;
    const int s   = blockIdx.x & 31;

    // ---- stage x chunk: 32 pixels x 128 floats, coalesced float4 ----
    const float4* xg4 = (const float4*)(x + (size_t)(b * 1024 + s * NPB) * 128);
#pragma unroll
    for (int i = 0; i < 4; ++i) {
        int f = tid + 256 * i;            // float4 index in chunk (1024 total)
        float4 v = xg4[f];
        *(float4*)&x_s[(f >> 5) * XS + (f & 31) * 4] = v;
    }

    // ---- codeword fragment in registers: lane(k,h) holds c[k][h*64 .. +63] ----
    const int lane = tid & 63;
    const int k    = lane & 31;
    const int h    = lane >> 5;
    const int w    = tid >> 6;

    float4 cf[16];
    const float4* cw4 = (const float4*)(cw + k * 128 + h * 64);
    float c2a = 0.f, c2b = 0.f;
#pragma unroll
    for (int i = 0; i < 16; i += 2) {
        float4 c0 = cw4[i], c1 = cw4[i + 1];
        cf[i] = c0; cf[i + 1] = c1;
        c2a += c0.x * c0.x + c0.y * c0.y + c0.z * c0.z + c0.w * c0.w;
        c2b += c1.x * c1.x + c1.y * c1.y + c1.z * c1.z + c1.w * c1.w;
    }
    float c2 = c2a + c2b;
    c2 += __shfl_xor(c2, 32);   // combine halves -> full ||c_k||^2 in both halves
    const float sck = scale[k];

    __syncthreads();

    // ---- pre-phase: x2[n] = ||x_n||^2 (8 threads per pixel) ----
    {
        int p = tid >> 3, q = tid & 7;
        float ss = 0.f;
#pragma unroll
        for (int i = 0; i < 4; ++i) {
            float4 v = *(const float4*)&x_s[p * XS + q * 16 + 4 * i];
            ss += v.x * v.x + v.y * v.y + v.z * v.z + v.w * v.w;
        }
        ss += __shfl_xor(ss, 1);
        ss += __shfl_xor(ss, 2);
        ss += __shfl_xor(ss, 4);
        if (q == 0) x2_s[p] = ss;
    }
    __syncthreads();

    // ---- phase 1: per-pixel softmax over K=32, one wave per 8 pixels ----
    float a_part = 0.f;
#pragma unroll
    for (int p = 0; p < 8; ++p) {
        const int n = (w << 3) + p;
        const float4* xr = (const float4*)&x_s[n * XS + h * 64];
        // 4 independent accumulators -> dependency chain of 16 FMAs, not 64
        float xc0 = 0.f, xc1 = 0.f, xc2 = 0.f, xc3 = 0.f;
#pragma unroll
        for (int i = 0; i < 16; i += 4) {
            float4 v0 = xr[i + 0], v1 = xr[i + 1], v2 = xr[i + 2], v3 = xr[i + 3];
            xc0 += v0.x * cf[i+0].x + v0.y * cf[i+0].y + v0.z * cf[i+0].z + v0.w * cf[i+0].w;
            xc1 += v1.x * cf[i+1].x + v1.y * cf[i+1].y + v1.z * cf[i+1].z + v1.w * cf[i+1].w;
            xc2 += v2.x * cf[i+2].x + v2.y * cf[i+2].y + v2.z * cf[i+2].z + v2.w * cf[i+2].w;
            xc3 += v3.x * cf[i+3].x + v3.y * cf[i+3].y + v3.z * cf[i+3].z + v3.w * cf[i+3].w;
        }
        float xc = (xc0 + xc1) + (xc2 + xc3);
        xc += __shfl_xor(xc, 32);   // combine d-halves -> full dot(x_n, c_k)

        float sl = sck * (x2_s[n] - 2.f * xc + c2);
        // softmax over k: butterfly within each 32-lane half (masks <= 16)
        float m = sl;
#pragma unroll
        for (int msk = 16; msk >= 1; msk >>= 1) m = fmaxf(m, __shfl_xor(m, msk));
        float e = __expf(sl - m);
        float den = e;
#pragma unroll
        for (int msk = 16; msk >= 1; msk >>= 1) den += __shfl_xor(den, msk);
        float a = e / den;
        A_s[n * 32 + k] = a;        // both halves write identical value (benign)
        a_part += a;
    }
    if (h == 0) asum_s[w * 32 + k] = a_part;
    __syncthreads();

    // ---- phase 2: E_part[k][d] = sum_n A[n][k] * x[n][d], 4k x 4d per thread ----
    {
        const int kg = tid >> 5;    // 0..7  -> k quad
        const int dg = tid & 31;    // 0..31 -> d quad
        float acc[4][4];
#pragma unroll
        for (int i = 0; i < 4; ++i)
#pragma unroll
            for (int j = 0; j < 4; ++j) acc[i][j] = 0.f;

#pragma unroll 8
        for (int n = 0; n < NPB; ++n) {
            float4 a4 = *(const float4*)&A_s[n * 32 + kg * 4];  // broadcast
            float4 x4 = *(const float4*)&x_s[n * XS + dg * 4];  // conflict-free
            acc[0][0] += a4.x * x4.x; acc[0][1] += a4.x * x4.y;
            acc[0][2] += a4.x * x4.z; acc[0][3] += a4.x * x4.w;
            acc[1][0] += a4.y * x4.x; acc[1][1] += a4.y * x4.y;
            acc[1][2] += a4.y * x4.z; acc[1][3] += a4.y * x4.w;
            acc[2][0] += a4.z * x4.x; acc[2][1] += a4.z * x4.y;
            acc[2][2] += a4.z * x4.z; acc[2][3] += a4.z * x4.w;
            acc[3][0] += a4.w * x4.x; acc[3][1] += a4.w * x4.y;
            acc[3][2] += a4.w * x4.z; acc[3][3] += a4.w * x4.w;
        }

        // fold in this block's partial -a_sum * c, store partial slice to ws
        float as[4];
#pragma unroll
        for (int i = 0; i < 4; ++i)
            as[i] = asum_s[kg * 4 + i] + asum_s[32 + kg * 4 + i] +
                    asum_s[64 + kg * 4 + i] + asum_s[96 + kg * 4 + i];

        float* wb = ws + (size_t)(b * 32 + s) * 4096;
#pragma unroll
        for (int i = 0; i < 4; ++i) {
            const int kk = kg * 4 + i;
            float4 c4 = *(const float4*)&cw[kk * 128 + dg * 4];
            float4 r;
            r.x = acc[i][0] - as[i] * c4.x;
            r.y = acc[i][1] - as[i] * c4.y;
            r.z = acc[i][2] - as[i] * c4.z;
            r.w = acc[i][3] - as[i] * c4.w;
            *(float4*)&wb[kk * 128 + dg * 4] = r;   // coalesced, no atomics
        }
    }
}

// Sum the 32 per-split slices per batch: out[b][j] = sum_s ws[(b*32+s)*4096 + j]
__global__ __launch_bounds__(256)
void enc_reduce(const float* __restrict__ ws, float* __restrict__ out)
{
    const int gid = blockIdx.x * 256 + threadIdx.x;   // 0..16383 float4-quads
    const int b   = gid >> 10;                        // 1024 quads per batch
    const int j4  = gid & 1023;
    const float4* base = (const float4*)ws + (size_t)b * 32768 + j4;
    float4 a0 = {0,0,0,0}, a1 = {0,0,0,0}, a2 = {0,0,0,0}, a3 = {0,0,0,0};
#pragma unroll
    for (int s = 0; s < 32; s += 4) {
        float4 v0 = base[(size_t)(s + 0) * 1024];
        float4 v1 = base[(size_t)(s + 1) * 1024];
        float4 v2 = base[(size_t)(s + 2) * 1024];
        float4 v3 = base[(size_t)(s + 3) * 1024];
        a0.x += v0.x; a0.y += v0.y; a0.z += v0.z; a0.w += v0.w;
        a1.x += v1.x; a1.y += v1.y; a1.z += v1.z; a1.w += v1.w;
        a2.x += v2.x; a2.y += v2.y; a2.z += v2.z; a2.w += v2.w;
        a3.x += v3.x; a3.y += v3.y; a3.z += v3.z; a3.w += v3.w;
    }
    float4 r;
    r.x = (a0.x + a1.x) + (a2.x + a3.x);
    r.y = (a0.y + a1.y) + (a2.y + a3.y);
    r.z = (a0.z + a1.z) + (a2.z + a3.z);
    r.w = (a0.w + a1.w) + (a2.w + a3.w);
    ((float4*)out)[gid] = r;
}

extern "C" void kernel_launch(void* const* d_in, const int* in_sizes, int n_in,
                              void* d_out, int out_size, void* d_ws, size_t ws_size,
                              hipStream_t stream)
{
    const float* x     = (const float*)d_in[0];  // [16,32,32,128]
    const float* cw    = (const float*)d_in[1];  // [32,128]
    const float* scale = (const float*)d_in[2];  // [32]
    float* out = (float*)d_out;                  // [16,32,128]
    float* ws  = (float*)d_ws;                   // uses 8 MB of workspace

    enc_partial<<<512, 256, 0, stream>>>(x, cw, scale, ws);
    enc_reduce<<<64, 256, 0, stream>>>(ws, out);
}

// Round 4
// 71.875 us; speedup vs baseline: 1.2243x; 1.0566x over previous
//
#include <hip/hip_runtime.h>

// EncodingLayer: B=16, N=1024 (32x32), D=128, K=32
//   A = softmax_k( scale_k * ||x_n - c_k||^2 )
//   E[b,k,d] = sum_n A[b,n,k]*x[b,n,d] - (sum_n A[b,n,k]) * c[k,d]
//
// k1: 512 blocks = 16 batches x 32 splits of 32 pixels (2 blocks/CU).
//     Phase 1 is now a register-tiled GEMM S = X*C^T (4n x 4k per thread,
//     d split 4 ways across waves) -> 1 flop/B of LDS delivery instead of
//     the 0.5 flop/B broadcast form; S (32x32) round-trips through LDS for
//     an 8-lane-shuffle softmax. a_sum is folded into phase 2's A reads.
// k2: 64 blocks x 256 threads sum the 32 slices per batch into d_out.

constexpr int XS = 132;   // padded LDS row stride (128+4) for x and c tiles

__global__ __launch_bounds__(256)
void enc_partial(const float* __restrict__ x, const float* __restrict__ cw,
                 const float* __restrict__ scale, float* __restrict__ ws)
{
    __shared__ float x_s[32 * XS];        // 16.9 KB
    __shared__ float c_s[32 * XS];        // 16.9 KB
    __shared__ float S_s[4 * 32 * 32];    // 16 KB  (d-quarter partials of X*C^T)
    __shared__ float A_s[32 * 32];        //  4 KB
    __shared__ float x2_s[32];
    __shared__ float c2_s[32];

    const int tid = threadIdx.x;
    const int b   = blockIdx.x >> 5;
    const int s   = blockIdx.x & 31;

    // ---- stage x chunk (32x128) and codewords (32x128), coalesced float4 ----
    const float4* xg4 = (const float4*)(x + (size_t)(b * 1024 + s * 32) * 128);
    const float4* cg4 = (const float4*)cw;
#pragma unroll
    for (int i = 0; i < 4; ++i) {
        int f = tid + 256 * i;            // float4 index (1024 total)
        float4 vx = xg4[f];
        float4 vc = cg4[f];
        *(float4*)&x_s[(f >> 5) * XS + (f & 31) * 4] = vx;
        *(float4*)&c_s[(f >> 5) * XS + (f & 31) * 4] = vc;
    }
    __syncthreads();

    // ---- pre-phase: x2[n] = ||x_n||^2 and c2[k] = ||c_k||^2 (8 thr/row) ----
    {
        const int p = tid >> 3, q = tid & 7;
        float sx = 0.f, sc = 0.f;
#pragma unroll
        for (int i = 0; i < 4; ++i) {
            float4 v = *(const float4*)&x_s[p * XS + q * 16 + 4 * i];
            float4 c = *(const float4*)&c_s[p * XS + q * 16 + 4 * i];
            sx += v.x * v.x + v.y * v.y + v.z * v.z + v.w * v.w;
            sc += c.x * c.x + c.y * c.y + c.z * c.z + c.w * c.w;
        }
        sx += __shfl_xor(sx, 1); sc += __shfl_xor(sc, 1);
        sx += __shfl_xor(sx, 2); sc += __shfl_xor(sc, 2);
        sx += __shfl_xor(sx, 4); sc += __shfl_xor(sc, 4);
        if (q == 0) { x2_s[p] = sx; c2_s[p] = sc; }
    }
    __syncthreads();

    // ---- phase 1a: S_part[dq][n][k] = sum_{d in quarter} x[n][d]*c[k][d] ----
    {
        const int dq = tid >> 6;          // 0..3  d-quarter (one per wave)
        const int kg = (tid >> 3) & 7;    // 0..7  k quad
        const int ng = tid & 7;           // 0..7  n quad
        float acc[4][4];
#pragma unroll
        for (int r = 0; r < 4; ++r)
#pragma unroll
            for (int c = 0; c < 4; ++c) acc[r][c] = 0.f;

#pragma unroll
        for (int i = 0; i < 8; ++i) {
            const int d4 = dq * 8 + i;    // float4 column
            float4 xv[4], cv[4];
#pragma unroll
            for (int r = 0; r < 4; ++r) {
                xv[r] = *(const float4*)&x_s[(ng * 4 + r) * XS + d4 * 4];
                cv[r] = *(const float4*)&c_s[(kg * 4 + r) * XS + d4 * 4];
            }
#pragma unroll
            for (int r = 0; r < 4; ++r)
#pragma unroll
                for (int c = 0; c < 4; ++c)
                    acc[r][c] += xv[r].x * cv[c].x + xv[r].y * cv[c].y +
                                 xv[r].z * cv[c].z + xv[r].w * cv[c].w;
        }
#pragma unroll
        for (int r = 0; r < 4; ++r) {
            float4 o = {acc[r][0], acc[r][1], acc[r][2], acc[r][3]};
            *(float4*)&S_s[(dq * 32 + ng * 4 + r) * 32 + kg * 4] = o;
        }
    }
    __syncthreads();

    // ---- phase 1b: softmax over k (thread = (row n, 4 k's); 8 lanes/row) ----
    {
        const int n = tid >> 3, j = tid & 7;
        float4 xc = {0.f, 0.f, 0.f, 0.f};
#pragma unroll
        for (int dq = 0; dq < 4; ++dq) {
            float4 v = *(const float4*)&S_s[(dq * 32 + n) * 32 + j * 4];
            xc.x += v.x; xc.y += v.y; xc.z += v.z; xc.w += v.w;
        }
        const float4 s4  = ((const float4*)scale)[j];
        const float4 c24 = *(const float4*)&c2_s[j * 4];
        const float x2n  = x2_s[n];
        float4 sl;
        sl.x = s4.x * (x2n - 2.f * xc.x + c24.x);
        sl.y = s4.y * (x2n - 2.f * xc.y + c24.y);
        sl.z = s4.z * (x2n - 2.f * xc.z + c24.z);
        sl.w = s4.w * (x2n - 2.f * xc.w + c24.w);
        float m = fmaxf(fmaxf(sl.x, sl.y), fmaxf(sl.z, sl.w));
        m = fmaxf(m, __shfl_xor(m, 1));
        m = fmaxf(m, __shfl_xor(m, 2));
        m = fmaxf(m, __shfl_xor(m, 4));
        float4 e;
        e.x = __expf(sl.x - m); e.y = __expf(sl.y - m);
        e.z = __expf(sl.z - m); e.w = __expf(sl.w - m);
        float den = (e.x + e.y) + (e.z + e.w);
        den += __shfl_xor(den, 1);
        den += __shfl_xor(den, 2);
        den += __shfl_xor(den, 4);
        const float rd = 1.f / den;
        float4 a = {e.x * rd, e.y * rd, e.z * rd, e.w * rd};
        *(float4*)&A_s[n * 32 + j * 4] = a;
    }
    __syncthreads();

    // ---- phase 2: E_part[k][d] = sum_n A[n][k]*x[n][d] (4k x 4d / thread),
    //      with a_sum[k] accumulated inline off the same A reads ----
    {
        const int kg = tid >> 5;    // 0..7  -> k quad
        const int dg = tid & 31;    // 0..31 -> d quad
        float acc[4][4];
        float as[4] = {0.f, 0.f, 0.f, 0.f};
#pragma unroll
        for (int i = 0; i < 4; ++i)
#pragma unroll
            for (int j = 0; j < 4; ++j) acc[i][j] = 0.f;

#pragma unroll 8
        for (int n = 0; n < 32; ++n) {
            float4 a4 = *(const float4*)&A_s[n * 32 + kg * 4];  // broadcast
            float4 x4 = *(const float4*)&x_s[n * XS + dg * 4];  // conflict-free
            acc[0][0] += a4.x * x4.x; acc[0][1] += a4.x * x4.y;
            acc[0][2] += a4.x * x4.z; acc[0][3] += a4.x * x4.w;
            acc[1][0] += a4.y * x4.x; acc[1][1] += a4.y * x4.y;
            acc[1][2] += a4.y * x4.z; acc[1][3] += a4.y * x4.w;
            acc[2][0] += a4.z * x4.x; acc[2][1] += a4.z * x4.y;
            acc[2][2] += a4.z * x4.z; acc[2][3] += a4.z * x4.w;
            acc[3][0] += a4.w * x4.x; acc[3][1] += a4.w * x4.y;
            acc[3][2] += a4.w * x4.z; acc[3][3] += a4.w * x4.w;
            as[0] += a4.x; as[1] += a4.y; as[2] += a4.z; as[3] += a4.w;
        }

        float* wb = ws + (size_t)(b * 32 + s) * 4096;
#pragma unroll
        for (int i = 0; i < 4; ++i) {
            const int kk = kg * 4 + i;
            float4 c4 = *(const float4*)&cw[kk * 128 + dg * 4];
            float4 r;
            r.x = acc[i][0] - as[i] * c4.x;
            r.y = acc[i][1] - as[i] * c4.y;
            r.z = acc[i][2] - as[i] * c4.z;
            r.w = acc[i][3] - as[i] * c4.w;
            *(float4*)&wb[kk * 128 + dg * 4] = r;   // coalesced, no atomics
        }
    }
}

// Sum the 32 per-split slices per batch: out[b][j] = sum_s ws[(b*32+s)*4096 + j]
__global__ __launch_bounds__(256)
void enc_reduce(const float* __restrict__ ws, float* __restrict__ out)
{
    const int gid = blockIdx.x * 256 + threadIdx.x;   // 0..16383 float4-quads
    const int b   = gid >> 10;                        // 1024 quads per batch
    const int j4  = gid & 1023;
    const float4* base = (const float4*)ws + (size_t)b * 32768 + j4;
    float4 a0 = {0,0,0,0}, a1 = {0,0,0,0}, a2 = {0,0,0,0}, a3 = {0,0,0,0};
#pragma unroll
    for (int s = 0; s < 32; s += 4) {
        float4 v0 = base[(size_t)(s + 0) * 1024];
        float4 v1 = base[(size_t)(s + 1) * 1024];
        float4 v2 = base[(size_t)(s + 2) * 1024];
        float4 v3 = base[(size_t)(s + 3) * 1024];
        a0.x += v0.x; a0.y += v0.y; a0.z += v0.z; a0.w += v0.w;
        a1.x += v1.x; a1.y += v1.y; a1.z += v1.z; a1.w += v1.w;
        a2.x += v2.x; a2.y += v2.y; a2.z += v2.z; a2.w += v2.w;
        a3.x += v3.x; a3.y += v3.y; a3.z += v3.z; a3.w += v3.w;
    }
    float4 r;
    r.x = (a0.x + a1.x) + (a2.x + a3.x);
    r.y = (a0.y + a1.y) + (a2.y + a3.y);
    r.z = (a0.z + a1.z) + (a2.z + a3.z);
    r.w = (a0.w + a1.w) + (a2.w + a3.w);
    ((float4*)out)[gid] = r;
}

extern "C" void kernel_launch(void* const* d_in, const int* in_sizes, int n_in,
                              void* d_out, int out_size, void* d_ws, size_t ws_size,
                              hipStream_t stream)
{
    const float* x     = (const float*)d_in[0];  // [16,32,32,128]
    const float* cw    = (const float*)d_in[1];  // [32,128]
    const float* scale = (const float*)d_in[2];  // [32]
    float* out = (float*)d_out;                  // [16,32,128]
    float* ws  = (float*)d_ws;                   // uses 8 MB of workspace

    enc_partial<<<512, 256, 0, stream>>>(x, cw, scale, ws);
    enc_reduce<<<64, 256, 0, stream>>>(ws, out);
}

// Round 5
// 71.112 us; speedup vs baseline: 1.2375x; 1.0107x over previous
//
#include <hip/hip_runtime.h>

// EncodingLayer: B=16, N=1024 (32x32), D=128, K=32
//   A = softmax_k( scale_k * ||x_n - c_k||^2 )
//   E[b,k,d] = sum_n A[b,n,k]*x[b,n,d] - (sum_n A[b,n,k]) * c[k,d]
//
// k1: 512 blocks = 16 batches x 32 splits of 32 pixels (2 blocks/CU).
//     Phase 1 S = X*C^T now via v_mfma_f32_32x32x16_bf16 (8 K-steps over
//     D=128); all 4 waves compute identical S in C-layout regs, wave w
//     softmaxes its regs 4w..4w+3 (rows 8w..8w+8) and writes A_s.
//     x2/c2 are computed in fp32 during staging via half-wave shuffles.
//     Phase 2 (E_part = A^T*X + -a_sum*c) stays fp32 vector (4k x 4d/thread).
// k2: 64 blocks x 256 threads sum the 32 slices per batch into d_out.

typedef __attribute__((ext_vector_type(8))) short bf16x8;   // 8 bf16 = 4 VGPRs
typedef __attribute__((ext_vector_type(16))) float f32x16;  // MFMA 32x32 C/D

constexpr int XS  = 132;  // fp32 x row stride (floats)
constexpr int XBS = 136;  // bf16 row stride (halfs) = 272 B, 16B-aligned rows

__device__ __forceinline__ unsigned short f2bf(float f) {
    unsigned u = __float_as_uint(f);
    u += 0x7fffu + ((u >> 16) & 1u);          // round-to-nearest-even
    return (unsigned short)(u >> 16);
}

__global__ __launch_bounds__(256)
void enc_partial(const float* __restrict__ x, const float* __restrict__ cw,
                 const float* __restrict__ scale, float* __restrict__ ws)
{
    __shared__ float          x_s[32 * XS];    // 16.9 KB fp32 X (phase 2)
    __shared__ unsigned short xb_s[32 * XBS];  //  8.5 KB bf16 X (MFMA A)
    __shared__ unsigned short cb_s[32 * XBS];  //  8.5 KB bf16 C (MFMA B)
    __shared__ float          A_s[32 * 32];    //  4.0 KB
    __shared__ float          x2_s[32];
    __shared__ float          c2_s[32];

    const int tid = threadIdx.x;
    const int b   = blockIdx.x >> 5;
    const int s   = blockIdx.x & 31;

    const float4* xg4 = (const float4*)(x + (size_t)(b * 1024 + s * 32) * 128);
    const float4* cg4 = (const float4*)cw;

    // ---- staging: fp32 + bf16 tiles, x2/c2 via half-wave shuffle reduce ----
    // f = tid + 256*i -> row = 8i + (tid>>5), col = tid&31 (full row per
    // 32-lane half -> shuffle-reduce row norms in registers).
#pragma unroll
    for (int i = 0; i < 4; ++i) {
        const int f   = tid + 256 * i;
        const int row = 8 * i + (tid >> 5);
        const int col = tid & 31;
        float4 vx = xg4[f];
        float4 vc = cg4[f];
        *(float4*)&x_s[row * XS + col * 4] = vx;
        short4 hx = { (short)f2bf(vx.x), (short)f2bf(vx.y),
                      (short)f2bf(vx.z), (short)f2bf(vx.w) };
        short4 hc = { (short)f2bf(vc.x), (short)f2bf(vc.y),
                      (short)f2bf(vc.z), (short)f2bf(vc.w) };
        *(short4*)&xb_s[row * XBS + col * 4] = hx;
        *(short4*)&cb_s[row * XBS + col * 4] = hc;
        float sx = vx.x * vx.x + vx.y * vx.y + vx.z * vx.z + vx.w * vx.w;
        float sc = vc.x * vc.x + vc.y * vc.y + vc.z * vc.z + vc.w * vc.w;
#pragma unroll
        for (int m = 16; m >= 1; m >>= 1) {
            sx += __shfl_xor(sx, m);
            sc += __shfl_xor(sc, m);
        }
        if ((tid & 31) == 0) { x2_s[row] = sx; c2_s[row] = sc; }
    }
    __syncthreads();

    // ---- phase 1a: S = X*C^T via MFMA (each wave computes full 32x32) ----
    // A frag: lane l holds X[m=l&31][k=t*16+(l>>5)*8+j]; B frag: lane l holds
    // C[kc=l&31][k same] (B_op[k][kc] = C^T). Contiguous b128 reads.
    const int lc = tid & 31;        // lane&31
    const int lh = (tid >> 5) & 1;  // lane>>5 within wave
    f32x16 acc;
#pragma unroll
    for (int i = 0; i < 16; ++i) acc[i] = 0.f;
#pragma unroll
    for (int t = 0; t < 8; ++t) {
        bf16x8 af = *(const bf16x8*)&xb_s[lc * XBS + t * 16 + lh * 8];
        bf16x8 bfr = *(const bf16x8*)&cb_s[lc * XBS + t * 16 + lh * 8];
        acc = __builtin_amdgcn_mfma_f32_32x32x16_bf16(af, bfr, acc, 0, 0, 0);
    }

    // ---- phase 1b: softmax over k (C-layout: col k = lc, row n per reg).
    // Wave w handles regs 4w+q -> rows n = q + 8w + 4*lh (all 32 rows covered).
    {
        const int w = tid >> 6;
        const float sck = scale[lc];
        const float c2k = c2_s[lc];
        const float4 x2v = *(const float4*)&x2_s[8 * w + 4 * lh];
        float sl[4] = {
            sck * (x2v.x - 2.f * acc[4 * w + 0] + c2k),
            sck * (x2v.y - 2.f * acc[4 * w + 1] + c2k),
            sck * (x2v.z - 2.f * acc[4 * w + 2] + c2k),
            sck * (x2v.w - 2.f * acc[4 * w + 3] + c2k) };
        float a[4];
#pragma unroll
        for (int q = 0; q < 4; ++q) {
            float m = sl[q];
#pragma unroll
            for (int msk = 16; msk >= 1; msk >>= 1) m = fmaxf(m, __shfl_xor(m, msk));
            float e = __expf(sl[q] - m);
            float den = e;
#pragma unroll
            for (int msk = 16; msk >= 1; msk >>= 1) den += __shfl_xor(den, msk);
            a[q] = e / den;
        }
#pragma unroll
        for (int q = 0; q < 4; ++q)
            A_s[(q + 8 * w + 4 * lh) * 32 + lc] = a[q];
    }
    __syncthreads();

    // ---- phase 2: E_part[k][d] = sum_n A[n][k]*x[n][d] (4k x 4d / thread),
    //      a_sum[k] folded into the same A reads ----
    {
        const int kg = tid >> 5;    // 0..7  -> k quad
        const int dg = tid & 31;    // 0..31 -> d quad
        float pacc[4][4];
        float as[4] = {0.f, 0.f, 0.f, 0.f};
#pragma unroll
        for (int i = 0; i < 4; ++i)
#pragma unroll
            for (int j = 0; j < 4; ++j) pacc[i][j] = 0.f;

#pragma unroll 8
        for (int n = 0; n < 32; ++n) {
            float4 a4 = *(const float4*)&A_s[n * 32 + kg * 4];  // broadcast
            float4 x4 = *(const float4*)&x_s[n * XS + dg * 4];  // conflict-free
            pacc[0][0] += a4.x * x4.x; pacc[0][1] += a4.x * x4.y;
            pacc[0][2] += a4.x * x4.z; pacc[0][3] += a4.x * x4.w;
            pacc[1][0] += a4.y * x4.x; pacc[1][1] += a4.y * x4.y;
            pacc[1][2] += a4.y * x4.z; pacc[1][3] += a4.y * x4.w;
            pacc[2][0] += a4.z * x4.x; pacc[2][1] += a4.z * x4.y;
            pacc[2][2] += a4.z * x4.z; pacc[2][3] += a4.z * x4.w;
            pacc[3][0] += a4.w * x4.x; pacc[3][1] += a4.w * x4.y;
            pacc[3][2] += a4.w * x4.z; pacc[3][3] += a4.w * x4.w;
            as[0] += a4.x; as[1] += a4.y; as[2] += a4.z; as[3] += a4.w;
        }

        float* wb = ws + (size_t)(b * 32 + s) * 4096;
#pragma unroll
        for (int i = 0; i < 4; ++i) {
            const int kk = kg * 4 + i;
            float4 c4 = *(const float4*)&cw[kk * 128 + dg * 4];
            float4 r;
            r.x = pacc[i][0] - as[i] * c4.x;
            r.y = pacc[i][1] - as[i] * c4.y;
            r.z = pacc[i][2] - as[i] * c4.z;
            r.w = pacc[i][3] - as[i] * c4.w;
            *(float4*)&wb[kk * 128 + dg * 4] = r;   // coalesced, no atomics
        }
    }
}

// Sum the 32 per-split slices per batch: out[b][j] = sum_s ws[(b*32+s)*4096 + j]
__global__ __launch_bounds__(256)
void enc_reduce(const float* __restrict__ ws, float* __restrict__ out)
{
    const int gid = blockIdx.x * 256 + threadIdx.x;   // 0..16383 float4-quads
    const int b   = gid >> 10;                        // 1024 quads per batch
    const int j4  = gid & 1023;
    const float4* base = (const float4*)ws + (size_t)b * 32768 + j4;
    float4 a0 = {0,0,0,0}, a1 = {0,0,0,0}, a2 = {0,0,0,0}, a3 = {0,0,0,0};
#pragma unroll
    for (int s = 0; s < 32; s += 4) {
        float4 v0 = base[(size_t)(s + 0) * 1024];
        float4 v1 = base[(size_t)(s + 1) * 1024];
        float4 v2 = base[(size_t)(s + 2) * 1024];
        float4 v3 = base[(size_t)(s + 3) * 1024];
        a0.x += v0.x; a0.y += v0.y; a0.z += v0.z; a0.w += v0.w;
        a1.x += v1.x; a1.y += v1.y; a1.z += v1.z; a1.w += v1.w;
        a2.x += v2.x; a2.y += v2.y; a2.z += v2.z; a2.w += v2.w;
        a3.x += v3.x; a3.y += v3.y; a3.z += v3.z; a3.w += v3.w;
    }
    float4 r;
    r.x = (a0.x + a1.x) + (a2.x + a3.x);
    r.y = (a0.y + a1.y) + (a2.y + a3.y);
    r.z = (a0.z + a1.z) + (a2.z + a3.z);
    r.w = (a0.w + a1.w) + (a2.w + a3.w);
    ((float4*)out)[gid] = r;
}

extern "C" void kernel_launch(void* const* d_in, const int* in_sizes, int n_in,
                              void* d_out, int out_size, void* d_ws, size_t ws_size,
                              hipStream_t stream)
{
    const float* x     = (const float*)d_in[0];  // [16,32,32,128]
    const float* cw    = (const float*)d_in[1];  // [32,128]
    const float* scale = (const float*)d_in[2];  // [32]
    float* out = (float*)d_out;                  // [16,32,128]
    float* ws  = (float*)d_ws;                   // uses 8 MB of workspace

    enc_partial<<<512, 256, 0, stream>>>(x, cw, scale, ws);
    enc_reduce<<<64, 256, 0, stream>>>(ws, out);
}

// Round 6
// 68.797 us; speedup vs baseline: 1.2791x; 1.0336x over previous
//
#include <hip/hip_runtime.h>

// EncodingLayer: B=16, N=1024 (32x32), D=128, K=32
//   A = softmax_k( scale_k * ||x_n - c_k||^2 )
//   E[b,k,d] = sum_n A[b,n,k]*x[b,n,d] - (sum_n A[b,n,k]) * c[k,d]
//
// k1: 512 blocks = 16 batches x 32 splits of 32 pixels (2 blocks/CU).
//     Phase 1a: S = X*C^T via v_mfma_f32_32x32x16_bf16 (8 K-steps, D=128),
//               all 4 waves redundantly compute S in C-layout regs.
//     Phase 1b: wave w softmaxes regs 4w..4w+3 (rows 8w+4lh..+4), writes
//               A^T bf16 (packed short4) + per-wave a_sum partials.
//     Phase 2:  E_part = A^T * X via 2 MFMAs per wave (wave = d-quarter);
//               A-frag b128 from At_s, B-frag 16x ds_read_u16 column reads
//               of xb_s. Epilogue folds -a_sum*c (fp32 c from global) and
//               stores bf16 partials to ws (4 MB total).
// k2: 64 blocks x 256 threads sum the 32 bf16 slices per batch into fp32 out.

typedef __attribute__((ext_vector_type(8))) short bf16x8;   // 8 bf16 = 4 VGPRs
typedef __attribute__((ext_vector_type(16))) float f32x16;  // MFMA 32x32 C/D

constexpr int XBS = 136;  // bf16 X/C row stride (shorts): 272 B, 16B-aligned
constexpr int AST = 40;   // A^T row stride (shorts): 80 B, 16B-aligned

__device__ __forceinline__ unsigned short f2bf(float f) {
    unsigned u = __float_as_uint(f);
    u += 0x7fffu + ((u >> 16) & 1u);          // round-to-nearest-even
    return (unsigned short)(u >> 16);
}
__device__ __forceinline__ float bf2f(unsigned short h) {
    return __uint_as_float((unsigned)h << 16);
}

__global__ __launch_bounds__(256)
void enc_partial(const float* __restrict__ x, const float* __restrict__ cw,
                 const float* __restrict__ scale, unsigned short* __restrict__ ws)
{
    __shared__ unsigned short xb_s[32 * XBS];  // 8.5 KB bf16 X
    __shared__ unsigned short cb_s[32 * XBS];  // 8.5 KB bf16 C
    __shared__ unsigned short At_s[32 * AST];  // 2.5 KB bf16 A^T [k][n]
    __shared__ float x2_s[32], c2_s[32];
    __shared__ float asum_s[4 * 32];           // per-wave a_sum partials
    __shared__ float asumf_s[32];              // final a_sum[k]

    const int tid = threadIdx.x;
    const int b   = blockIdx.x >> 5;
    const int s   = blockIdx.x & 31;
    const int lc  = tid & 31;        // lane&31
    const int lh  = (tid >> 5) & 1;  // lane>>5 within wave
    const int w   = tid >> 6;        // wave id

    const float4* xg4 = (const float4*)(x + (size_t)(b * 1024 + s * 32) * 128);
    const float4* cg4 = (const float4*)cw;

    // ---- staging: bf16 tiles + row norms via half-wave shuffle reduce ----
#pragma unroll
    for (int i = 0; i < 4; ++i) {
        const int f   = tid + 256 * i;
        const int row = 8 * i + (tid >> 5);
        const int col = tid & 31;
        float4 vx = xg4[f];
        float4 vc = cg4[f];
        short4 hx = { (short)f2bf(vx.x), (short)f2bf(vx.y),
                      (short)f2bf(vx.z), (short)f2bf(vx.w) };
        short4 hc = { (short)f2bf(vc.x), (short)f2bf(vc.y),
                      (short)f2bf(vc.z), (short)f2bf(vc.w) };
        *(short4*)&xb_s[row * XBS + col * 4] = hx;
        *(short4*)&cb_s[row * XBS + col * 4] = hc;
        float sx = vx.x * vx.x + vx.y * vx.y + vx.z * vx.z + vx.w * vx.w;
        float sc = vc.x * vc.x + vc.y * vc.y + vc.z * vc.z + vc.w * vc.w;
#pragma unroll
        for (int m = 16; m >= 1; m >>= 1) {
            sx += __shfl_xor(sx, m);
            sc += __shfl_xor(sc, m);
        }
        if (col == 0) { x2_s[row] = sx; c2_s[row] = sc; }
    }
    __syncthreads();

    // ---- phase 1a: S = X*C^T via MFMA (each wave computes full 32x32) ----
    f32x16 acc;
#pragma unroll
    for (int i = 0; i < 16; ++i) acc[i] = 0.f;
#pragma unroll
    for (int t = 0; t < 8; ++t) {
        bf16x8 af  = *(const bf16x8*)&xb_s[lc * XBS + t * 16 + lh * 8];
        bf16x8 bfr = *(const bf16x8*)&cb_s[lc * XBS + t * 16 + lh * 8];
        acc = __builtin_amdgcn_mfma_f32_32x32x16_bf16(af, bfr, acc, 0, 0, 0);
    }

    // ---- phase 1b: softmax over k; write A^T bf16 + a_sum partials ----
    // C-layout: col k = lc, row n = (reg&3) + 8*(reg>>2) + 4*lh; wave w uses
    // regs 4w+q -> rows n = q + 8w + 4lh (the 4 waves cover all 32 rows).
    {
        const float sck = scale[lc];
        const float c2k = c2_s[lc];
        const float4 x2v = *(const float4*)&x2_s[8 * w + 4 * lh];
        float sl[4] = {
            sck * (x2v.x - 2.f * acc[4 * w + 0] + c2k),
            sck * (x2v.y - 2.f * acc[4 * w + 1] + c2k),
            sck * (x2v.z - 2.f * acc[4 * w + 2] + c2k),
            sck * (x2v.w - 2.f * acc[4 * w + 3] + c2k) };
        float a[4];
#pragma unroll
        for (int q = 0; q < 4; ++q) {
            float m = sl[q];
#pragma unroll
            for (int msk = 16; msk >= 1; msk >>= 1) m = fmaxf(m, __shfl_xor(m, msk));
            float e = __expf(sl[q] - m);
            float den = e;
#pragma unroll
            for (int msk = 16; msk >= 1; msk >>= 1) den += __shfl_xor(den, msk);
            a[q] = e / den;
        }
        // A^T[k=lc][n = 8w+4lh + q], q=0..3 consecutive -> one packed short4
        short4 ha = { (short)f2bf(a[0]), (short)f2bf(a[1]),
                      (short)f2bf(a[2]), (short)f2bf(a[3]) };
        *(short4*)&At_s[lc * AST + 8 * w + 4 * lh] = ha;
        float ap = (a[0] + a[1]) + (a[2] + a[3]);
        ap += __shfl_xor(ap, 32);          // combine lh halves -> 8-row partial
        if (lh == 0) asum_s[w * 32 + lc] = ap;
    }
    __syncthreads();

    // finalize a_sum[k] (threads 0..31) while others start phase-2 MFMA
    if (tid < 32)
        asumf_s[tid] = (asum_s[tid] + asum_s[32 + tid]) +
                       (asum_s[64 + tid] + asum_s[96 + tid]);

    // ---- phase 2: E_part = A^T * X via MFMA; wave w = d-quarter ----
    // A-frag: lane holds A^T[kk=lc][n = t*16+lh*8+j] (b128 from At_s).
    // B-frag: lane holds X[n = t*16+lh*8+j][dd = 32w+lc] (u16 column reads).
    f32x16 e;
#pragma unroll
    for (int i = 0; i < 16; ++i) e[i] = 0.f;
#pragma unroll
    for (int t = 0; t < 2; ++t) {
        bf16x8 af = *(const bf16x8*)&At_s[lc * AST + t * 16 + lh * 8];
        const int nb = t * 16 + lh * 8;
        bf16x8 bfr;
#pragma unroll
        for (int j = 0; j < 8; ++j)
            bfr[j] = (short)xb_s[(nb + j) * XBS + w * 32 + lc];
        e = __builtin_amdgcn_mfma_f32_32x32x16_bf16(af, bfr, e, 0, 0, 0);
    }
    __syncthreads();   // asumf_s ready for everyone

    // ---- epilogue: fold -a_sum*c, store bf16 partial slice ----
    {
        unsigned short* wb = ws + (size_t)(b * 32 + s) * 4096;
        const int dd = w * 32 + lc;
#pragma unroll
        for (int r = 0; r < 16; ++r) {
            const int kk = (r & 3) + 8 * (r >> 2) + 4 * lh;
            float v = e[r] - asumf_s[kk] * cw[kk * 128 + dd];
            wb[kk * 128 + dd] = f2bf(v);   // coalesced 64B/half-wave
        }
    }
}

// Sum the 32 bf16 slices per batch: out[b][j] = sum_s ws[(b*32+s)*4096 + j]
__global__ __launch_bounds__(256)
void enc_reduce(const unsigned short* __restrict__ ws, float* __restrict__ out)
{
    const int gid = blockIdx.x * 256 + threadIdx.x;   // 0..16383 quad ids
    const int b   = gid >> 10;                        // 1024 quads per batch
    const int j4  = (gid & 1023) * 4;
    const unsigned short* base = ws + (size_t)b * 131072 + j4;
    float4 a0 = {0,0,0,0}, a1 = {0,0,0,0}, a2 = {0,0,0,0}, a3 = {0,0,0,0};
#pragma unroll
    for (int s = 0; s < 32; s += 4) {
        ushort4 v0 = *(const ushort4*)&base[(s + 0) * 4096];
        ushort4 v1 = *(const ushort4*)&base[(s + 1) * 4096];
        ushort4 v2 = *(const ushort4*)&base[(s + 2) * 4096];
        ushort4 v3 = *(const ushort4*)&base[(s + 3) * 4096];
        a0.x += bf2f(v0.x); a0.y += bf2f(v0.y); a0.z += bf2f(v0.z); a0.w += bf2f(v0.w);
        a1.x += bf2f(v1.x); a1.y += bf2f(v1.y); a1.z += bf2f(v1.z); a1.w += bf2f(v1.w);
        a2.x += bf2f(v2.x); a2.y += bf2f(v2.y); a2.z += bf2f(v2.z); a2.w += bf2f(v2.w);
        a3.x += bf2f(v3.x); a3.y += bf2f(v3.y); a3.z += bf2f(v3.z); a3.w += bf2f(v3.w);
    }
    float4 r;
    r.x = (a0.x + a1.x) + (a2.x + a3.x);
    r.y = (a0.y + a1.y) + (a2.y + a3.y);
    r.z = (a0.z + a1.z) + (a2.z + a3.z);
    r.w = (a0.w + a1.w) + (a2.w + a3.w);
    *(float4*)&out[(size_t)b * 4096 + j4] = r;
}

extern "C" void kernel_launch(void* const* d_in, const int* in_sizes, int n_in,
                              void* d_out, int out_size, void* d_ws, size_t ws_size,
                              hipStream_t stream)
{
    const float* x     = (const float*)d_in[0];  // [16,32,32,128]
    const float* cw    = (const float*)d_in[1];  // [32,128]
    const float* scale = (const float*)d_in[2];  // [32]
    float* out = (float*)d_out;                  // [16,32,128]
    unsigned short* ws = (unsigned short*)d_ws;  // 4 MB bf16 partials

    enc_partial<<<512, 256, 0, stream>>>(x, cw, scale, ws);
    enc_reduce<<<64, 256, 0, stream>>>(ws, out);
}